// Round 9
// baseline (1899.379 us; speedup 1.0000x reference)
//
#include <hip/hip_runtime.h>
#include <hip/hip_bf16.h>

#define NODES 100000
#define EDGES 1600000
#define NGRAPH 512
#define NTILES 98  // ceil(100001 / 1024)

using bf16 = __hip_bfloat16;
typedef long long ll;

__device__ __forceinline__ float lrelu(float v) { return v > 0.0f ? v : 0.2f * v; }

__device__ __forceinline__ unsigned mapf(float f) {
    unsigned u = __float_as_uint(f);
    return (u & 0x80000000u) ? ~u : (u | 0x80000000u);
}
__device__ __forceinline__ float unmapf(unsigned u) {
    return __uint_as_float((u & 0x80000000u) ? (u ^ 0x80000000u) : ~u);
}

__device__ __forceinline__ int idx_at(const void* raw, int i, int f) {
    return f ? (int)((const ll*)raw)[i] : ((const int*)raw)[i];
}

__global__ void detect_int64(const int* __restrict__ w, int* __restrict__ flag) {
    __shared__ int red[4];
    int t = threadIdx.x;
    int v = 0;
    for (int i = t; i < 4096; i += 256) v |= w[2 * i + 1];
    for (int o = 32; o; o >>= 1) v |= __shfl_xor(v, o);
    if ((t & 63) == 0) red[t >> 6] = v;
    __syncthreads();
    if (t == 0) flag[0] = ((red[0] | red[1] | red[2] | red[3]) == 0) ? 1 : 0;
}

__global__ void sentinel_kernel(float* out, float v) {
    int i = blockIdx.x * blockDim.x + threadIdx.x;
    if (i < NGRAPH * 10) out[i] = v;
}

__global__ void init_kernel(int* __restrict__ deg, unsigned* __restrict__ pooled) {
    int i = blockIdx.x * blockDim.x + threadIdx.x;
    if (i < NODES) deg[i] = 0;
    if (i < NGRAPH * 64) pooled[i] = mapf(-1e4f);
}

// degree over dst; require BOTH endpoints valid so fill_csr fills every slot
__global__ void degree_kernel(const void* __restrict__ ei, const int* __restrict__ flag,
                              int* __restrict__ deg) {
    int i = blockIdx.x * blockDim.x + threadIdx.x;
    if (i >= EDGES) return;
    int f = flag[0];
    int s = idx_at(ei, i, f), d = idx_at(ei, EDGES + i, f);
    if ((unsigned)s < NODES && (unsigned)d < NODES) atomicAdd(&deg[d], 1);
}

// fused: dinv1/dinv2 + xs = bf16(x * dinv1)
__global__ void dinv_prescale(const int* __restrict__ deg, const float* __restrict__ x,
                              float* __restrict__ dinv1, float* __restrict__ dinv2,
                              bf16* __restrict__ xs) {
    int wave = threadIdx.x >> 6, lane = threadIdx.x & 63;
    int row = blockIdx.x * 4 + wave;
    if (row >= NODES) return;
    float cdeg = (float)deg[row];
    float d1 = 1.0f / sqrtf(cdeg + 2.0f);
    float d2 = 1.0f / sqrtf(cdeg + 1.0f);
    if (lane == 0) { dinv1[row] = d1; dinv2[row] = d2; }
    xs[(size_t)row * 64 + lane] = __float2bfloat16(x[(size_t)row * 64 + lane] * d1);
}

// ---- exclusive scan of deg -> row_ptr (+ cursor copy) ----
__global__ void scanA(const int* __restrict__ deg, int* __restrict__ blocksum) {
    __shared__ int red[4];
    int b = blockIdx.x, t = threadIdx.x;
    int base = b * 1024;
    int s = 0;
#pragma unroll
    for (int k = 0; k < 4; ++k) {
        int i = base + t + k * 256;
        if (i < NODES) s += deg[i];
    }
    for (int o = 32; o; o >>= 1) s += __shfl_xor(s, o);
    if ((t & 63) == 0) red[t >> 6] = s;
    __syncthreads();
    if (t == 0) blocksum[b] = red[0] + red[1] + red[2] + red[3];
}

__global__ void scanB(const int* __restrict__ blocksum, int* __restrict__ blockoff) {
    __shared__ int sc[128];
    int t = threadIdx.x;
    int v = (t < NTILES) ? blocksum[t] : 0;
    sc[t] = v;
    __syncthreads();
    for (int o = 1; o < 128; o <<= 1) {
        int u = (t >= o) ? sc[t - o] : 0;
        __syncthreads();
        sc[t] += u;
        __syncthreads();
    }
    if (t < NTILES) blockoff[t] = sc[t] - v;  // exclusive
}

__global__ void scanC(const int* __restrict__ deg, const int* __restrict__ blockoff,
                      int* __restrict__ row_ptr, int* __restrict__ cursor) {
    __shared__ int sc[256];
    int b = blockIdx.x, t = threadIdx.x;
    int base = b * 1024 + t * 4;
    int v[4];
#pragma unroll
    for (int k = 0; k < 4; ++k) {
        int i = base + k;
        v[k] = (i < NODES) ? deg[i] : 0;
    }
    int tsum = v[0] + v[1] + v[2] + v[3];
    sc[t] = tsum;
    __syncthreads();
    for (int o = 1; o < 256; o <<= 1) {
        int u = (t >= o) ? sc[t - o] : 0;
        __syncthreads();
        sc[t] += u;
        __syncthreads();
    }
    int excl = sc[t] - tsum + blockoff[b];
#pragma unroll
    for (int k = 0; k < 4; ++k) {
        int i = base + k;
        if (i <= NODES) row_ptr[i] = excl;
        if (i < NODES) cursor[i] = excl;
        excl += v[k];
    }
}
// ----------------------------------------------------------

__global__ void fill_csr(const void* __restrict__ ei, const int* __restrict__ flag,
                         int* __restrict__ cursor, int* __restrict__ csr_src) {
    int i = blockIdx.x * blockDim.x + threadIdx.x;
    if (i >= EDGES) return;
    int f = flag[0];
    int s = idx_at(ei, i, f), d = idx_at(ei, EDGES + i, f);
    if ((unsigned)s >= NODES || (unsigned)d >= NODES) return;
    int slot = atomicAdd(&cursor[d], 1);  // cursor pre-seeded with row_ptr
    csr_src[slot] = s;
}

// ---- 4-rows-per-wave fused GCN layer body ----
// Each wave processes rows r0..r0+3. Lane: h=lane>>5 (edge parity), c=lane&31
// (column pair). Four gather chains run interleaved for MLP.
template <bool LAYER1>
__device__ __forceinline__ void gcn_quad(
    const unsigned* __restrict__ feat2, const int* __restrict__ csr,
    const int* __restrict__ rp, const float* __restrict__ dinvA, int r0, int lane,
    const float* __restrict__ Wl /*LDS 4096*/, const float* __restrict__ bias,
    float selfw, float (&a)[4]) {
    int h = lane >> 5, c = lane & 31;
    // one lane-parallel load covers rp for all 4 rows
    int rpv = (lane < 5) ? rp[r0 + lane] : 0;
    int beg[4], cnt[4], cntA[4];
    int idx[4];
#pragma unroll
    for (int r = 0; r < 4; ++r) {
        beg[r] = __shfl(rpv, r);
        int end = __shfl(rpv, r + 1);
        cnt[r] = end - beg[r];
        cntA[r] = min(64, cnt[r]);
        idx[r] = (lane < cnt[r]) ? csr[beg[r] + lane] : 0;  // 4 independent loads
    }
    float vx[4] = {0, 0, 0, 0}, vy[4] = {0, 0, 0, 0};
    int jmax = max(max(cntA[0], cntA[1]), max(cntA[2], cntA[3]));
    for (int j = 0; j < jmax; j += 2) {
        int e = j + h;
#pragma unroll
        for (int r = 0; r < 4; ++r) {
            if (j < cntA[r]) {  // wave-uniform per r
                int s = __shfl(idx[r], e);  // 0 (safe) when e >= cnt
                unsigned u = feat2[(size_t)s * 32 + c];
                if (e < cntA[r]) {  // per-half predicate
                    vx[r] += __uint_as_float(u << 16);
                    vy[r] += __uint_as_float(u & 0xffff0000u);
                }
            }
        }
    }
    // rare fallback: degree > 64
#pragma unroll
    for (int r = 0; r < 4; ++r) {
        if (cnt[r] > 64) {
            int end = beg[r] + cnt[r];
            for (int cb = beg[r] + 64; cb < end; cb += 64) {
                int cc2 = min(64, end - cb);
                int idx2 = (cb + lane < end) ? csr[cb + lane] : 0;
                for (int j = 0; j < cc2; j += 2) {
                    int e = j + h;
                    int s = __shfl(idx2, e);
                    unsigned u = feat2[(size_t)s * 32 + c];
                    if (e < cc2) {
                        vx[r] += __uint_as_float(u << 16);
                        vy[r] += __uint_as_float(u & 0xffff0000u);
                    }
                }
            }
        }
    }
    // merge halves, add self-loop, scale by dinv[dst]
    float dvv = (lane < 4) ? dinvA[r0 + lane] : 0.0f;
    unsigned us[4];
#pragma unroll
    for (int r = 0; r < 4; ++r) us[r] = feat2[(size_t)(r0 + r) * 32 + c];
#pragma unroll
    for (int r = 0; r < 4; ++r) {
        vx[r] += __shfl_xor(vx[r], 32);
        vy[r] += __shfl_xor(vy[r], 32);
        float dv = __shfl(dvv, r);
        vx[r] = dv * (vx[r] + selfw * __uint_as_float(us[r] << 16));
        vy[r] = dv * (vy[r] + selfw * __uint_as_float(us[r] & 0xffff0000u));
    }
    // GEMM: W LDS reads shared across the 4 rows
    float bl = bias[lane];
#pragma unroll
    for (int r = 0; r < 4; ++r) a[r] = bl;
#pragma unroll
    for (int cc = 0; cc < 32; ++cc) {
        float w0 = Wl[(2 * cc) * 64 + lane];
        float w1 = Wl[(2 * cc + 1) * 64 + lane];
#pragma unroll
        for (int r = 0; r < 4; ++r)
            a[r] += __shfl(vx[r], cc) * w0 + __shfl(vy[r], cc) * w1;
    }
}

// fused layer1: gather(xs) + self*2 + @W1 + b1 + LN + leaky -> h1s = h1*dinv2
__global__ void gcn1_fused(const unsigned* __restrict__ xs2, const int* __restrict__ csr,
                           const int* __restrict__ rp, const float* __restrict__ dinv1,
                           const float* __restrict__ dinv2, const float* __restrict__ W1,
                           const float* __restrict__ b1, const float* __restrict__ lng,
                           const float* __restrict__ lnb, bf16* __restrict__ h1s) {
    __shared__ float Wl[4096];
    int t = threadIdx.x;
    for (int i = t; i < 4096; i += 256) Wl[i] = W1[i];
    __syncthreads();
    int lane = t & 63, wave = t >> 6;
    int r0 = (blockIdx.x * 4 + wave) * 4;
    if (r0 >= NODES) return;
    float a[4];
    gcn_quad<true>(xs2, csr, rp, dinv1, r0, lane, Wl, b1, 2.0f, a);
    float lg = lng[lane], lb = lnb[lane];
    float d2v = (lane < 4) ? dinv2[r0 + lane] : 0.0f;
#pragma unroll
    for (int r = 0; r < 4; ++r) {
        float s = a[r];
        for (int o = 32; o; o >>= 1) s += __shfl_xor(s, o);
        float mu = s * (1.0f / 64.0f);
        float d = a[r] - mu;
        float q = d * d;
        for (int o = 32; o; o >>= 1) q += __shfl_xor(q, o);
        float var = q * (1.0f / 64.0f);
        float y = d / sqrtf(var + 1e-5f) * lg + lb;
        h1s[(size_t)(r0 + r) * 64 + lane] = __float2bfloat16(lrelu(y) * __shfl(d2v, r));
    }
}

// fused layer2: gather(h1s) + self + @W2 + b2 + leaky + run-merged max-pool
__global__ void gcn2_fused(const unsigned* __restrict__ h1s2, const int* __restrict__ csr,
                           const int* __restrict__ rp, const float* __restrict__ dinv2,
                           const float* __restrict__ W2, const float* __restrict__ b2,
                           const void* __restrict__ batch, const int* __restrict__ flag,
                           unsigned* __restrict__ pooled) {
    __shared__ float Wl[4096];
    int t = threadIdx.x;
    for (int i = t; i < 4096; i += 256) Wl[i] = W2[i];
    __syncthreads();
    int lane = t & 63, wave = t >> 6;
    int r0 = (blockIdx.x * 4 + wave) * 4;
    if (r0 >= NODES) return;
    float a[4];
    gcn_quad<false>(h1s2, csr, rp, dinv2, r0, lane, Wl, b2, 1.0f, a);
    int f = flag[0];
    int gv = (lane < 4) ? idx_at(batch, r0 + lane, f) : 0;
    int g[4];
#pragma unroll
    for (int r = 0; r < 4; ++r) {
        a[r] = lrelu(a[r]);
        g[r] = __shfl(gv, r);
    }
    // run-merge consecutive rows with identical graph id (batch is sorted)
    float m = a[0];
    int gc = g[0];
#pragma unroll
    for (int r = 1; r < 4; ++r) {
        if (g[r] == gc) {
            m = fmaxf(m, a[r]);
        } else {
            if ((unsigned)gc < NGRAPH) atomicMax(&pooled[gc * 64 + lane], mapf(m));
            gc = g[r];
            m = a[r];
        }
    }
    if ((unsigned)gc < NGRAPH) atomicMax(&pooled[gc * 64 + lane], mapf(m));
}

// head: z = pooled@W3+b3; LN; leaky; z@W4+b4; softmax. One block per graph.
__global__ void head_kernel(const unsigned* __restrict__ pooled, const float* __restrict__ W3,
                            const float* __restrict__ b3, const float* __restrict__ g2,
                            const float* __restrict__ be2, const float* __restrict__ W4,
                            const float* __restrict__ b4, float* __restrict__ out) {
    __shared__ float prow[64];
    __shared__ float z[768];
    __shared__ float rs[4], rss[4];
    __shared__ float mu_s, rstd_s;
    __shared__ float red[10];
    int t = threadIdx.x, gI = blockIdx.x;
    if (t < 64) prow[t] = unmapf(pooled[gI * 64 + t]);
    __syncthreads();
    for (int c = t; c < 768; c += 256) {
        float acc = b3[c];
#pragma unroll 16
        for (int k = 0; k < 64; ++k) acc += prow[k] * W3[k * 768 + c];
        z[c] = acc;
    }
    __syncthreads();
    float s = 0.0f, ss = 0.0f;
    for (int c = t; c < 768; c += 256) {
        float v = z[c];
        s += v;
        ss += v * v;
    }
    for (int o = 32; o; o >>= 1) {
        s += __shfl_xor(s, o);
        ss += __shfl_xor(ss, o);
    }
    if ((t & 63) == 0) { rs[t >> 6] = s; rss[t >> 6] = ss; }
    __syncthreads();
    if (t == 0) {
        float S = rs[0] + rs[1] + rs[2] + rs[3];
        float SS = rss[0] + rss[1] + rss[2] + rss[3];
        float mu = S * (1.0f / 768.0f);
        float var = SS * (1.0f / 768.0f) - mu * mu;
        mu_s = mu;
        rstd_s = 1.0f / sqrtf(fmaxf(var, 0.0f) + 1e-5f);
    }
    __syncthreads();
    for (int c = t; c < 768; c += 256) {
        float y = (z[c] - mu_s) * rstd_s * g2[c] + be2[c];
        z[c] = lrelu(y);
    }
    if (t < 10) red[t] = 0.0f;
    __syncthreads();
    float p[10];
#pragma unroll
    for (int c = 0; c < 10; ++c) p[c] = 0.0f;
    for (int k = t; k < 768; k += 256) {
        float zv = z[k];
#pragma unroll
        for (int c = 0; c < 10; ++c) p[c] += zv * W4[k * 10 + c];
    }
#pragma unroll
    for (int c = 0; c < 10; ++c) atomicAdd(&red[c], p[c]);
    __syncthreads();
    if (t == 0) {
        float l[10], m = -1e30f;
#pragma unroll
        for (int c = 0; c < 10; ++c) {
            l[c] = red[c] + b4[c];
            m = fmaxf(m, l[c]);
        }
        float sum = 0.0f;
#pragma unroll
        for (int c = 0; c < 10; ++c) {
            l[c] = expf(l[c] - m);
            sum += l[c];
        }
        float inv = 1.0f / sum;
#pragma unroll
        for (int c = 0; c < 10; ++c) out[gI * 10 + c] = l[c] * inv;
    }
}

extern "C" void kernel_launch(void* const* d_in, const int* in_sizes, int n_in,
                              void* d_out, int out_size, void* d_ws, size_t ws_size,
                              hipStream_t stream) {
    const size_t REQUIRED = (size_t)NODES * 64 * 2 * 2  // xs + h1s (bf16)
                          + (size_t)EDGES * 4           // csr_src
                          + (size_t)(NODES + 1) * 4     // row_ptr
                          + (size_t)NODES * 4 * 4       // cursor, deg, dinv1, dinv2
                          + (size_t)NTILES * 4 * 2      // blocksum, blockoff
                          + (size_t)NGRAPH * 64 * 4     // pooled
                          + 16;                         // flag
    if (ws_size < REQUIRED) {
        sentinel_kernel<<<20, 256, 0, stream>>>((float*)d_out, 64.0f);
        return;
    }

    const float* x = (const float*)d_in[0];
    const void* ei = d_in[1];
    const void* batch = d_in[2];
    const float* W1 = (const float*)d_in[3];
    const float* b1 = (const float*)d_in[4];
    const float* lng = (const float*)d_in[5];
    const float* lnb = (const float*)d_in[6];
    const float* W2 = (const float*)d_in[7];
    const float* b2 = (const float*)d_in[8];
    const float* W3 = (const float*)d_in[9];
    const float* b3 = (const float*)d_in[10];
    const float* g2 = (const float*)d_in[11];
    const float* be2 = (const float*)d_in[12];
    const float* W4 = (const float*)d_in[13];
    const float* b4 = (const float*)d_in[14];

    bf16* xs = (bf16*)d_ws;                               // N*64 bf16
    bf16* h1s = xs + (size_t)NODES * 64;                  // N*64 bf16
    int* csr_src = (int*)(h1s + (size_t)NODES * 64);      // E
    int* row_ptr = csr_src + EDGES;                       // N+1
    int* cursor = row_ptr + (NODES + 1);                  // N
    int* deg = cursor + NODES;                            // N
    float* dinv1 = (float*)(deg + NODES);                 // N
    float* dinv2 = dinv1 + NODES;                         // N
    int* blocksum = (int*)(dinv2 + NODES);                // NTILES
    int* blockoff = blocksum + NTILES;                    // NTILES
    unsigned* pooled = (unsigned*)(blockoff + NTILES);    // G*64
    int* flag = (int*)(pooled + NGRAPH * 64);             // 1

    detect_int64<<<1, 256, 0, stream>>>((const int*)ei, flag);
    init_kernel<<<(NODES + 255) / 256, 256, 0, stream>>>(deg, pooled);

    // CSR build
    degree_kernel<<<(EDGES + 255) / 256, 256, 0, stream>>>(ei, flag, deg);
    dinv_prescale<<<(NODES + 3) / 4, 256, 0, stream>>>(deg, x, dinv1, dinv2, xs);
    scanA<<<NTILES, 256, 0, stream>>>(deg, blocksum);
    scanB<<<1, 128, 0, stream>>>(blocksum, blockoff);
    scanC<<<NTILES, 256, 0, stream>>>(deg, blockoff, row_ptr, cursor);
    fill_csr<<<(EDGES + 255) / 256, 256, 0, stream>>>(ei, flag, cursor, csr_src);

    // fused layers: 4 waves/block, 4 rows/wave -> 16 rows/block
    gcn1_fused<<<(NODES + 15) / 16, 256, 0, stream>>>((const unsigned*)xs, csr_src, row_ptr,
                                                      dinv1, dinv2, W1, b1, lng, lnb, h1s);
    gcn2_fused<<<(NODES + 15) / 16, 256, 0, stream>>>((const unsigned*)h1s, csr_src, row_ptr,
                                                      dinv2, W2, b2, batch, flag, pooled);

    // head
    head_kernel<<<NGRAPH, 256, 0, stream>>>(pooled, W3, b3, g2, be2, W4, b4, (float*)d_out);
}

// Round 10
// 605.194 us; speedup vs baseline: 3.1385x; 3.1385x over previous
//
#include <hip/hip_runtime.h>
#include <hip/hip_bf16.h>

#define NODES 100000
#define EDGES 1600000
#define NGRAPH 512
#define NTILES 98  // ceil(100001 / 1024)

using bf16 = __hip_bfloat16;
typedef long long ll;

__device__ __forceinline__ float lrelu(float v) { return v > 0.0f ? v : 0.2f * v; }

__device__ __forceinline__ unsigned mapf(float f) {
    unsigned u = __float_as_uint(f);
    return (u & 0x80000000u) ? ~u : (u | 0x80000000u);
}
__device__ __forceinline__ float unmapf(unsigned u) {
    return __uint_as_float((u & 0x80000000u) ? (u ^ 0x80000000u) : ~u);
}

__device__ __forceinline__ int idx_at(const void* raw, int i, int f) {
    return f ? (int)((const ll*)raw)[i] : ((const int*)raw)[i];
}

__global__ void sentinel_kernel(float* out, float v) {
    int i = blockIdx.x * blockDim.x + threadIdx.x;
    if (i < NGRAPH * 10) out[i] = v;
}

// fused: int64-detect (block 0) + deg=0 + pooled=sentinel
__global__ void detect_init(const int* __restrict__ w, int* __restrict__ flag,
                            int* __restrict__ deg, unsigned* __restrict__ pooled) {
    int i = blockIdx.x * blockDim.x + threadIdx.x;
    if (i < NODES) deg[i] = 0;
    if (i < NGRAPH * 64) pooled[i] = mapf(-1e4f);
    if (blockIdx.x == 0) {
        __shared__ int red[4];
        int t = threadIdx.x;
        int v = 0;
        for (int k = t; k < 4096; k += 256) v |= w[2 * k + 1];
        for (int o = 32; o; o >>= 1) v |= __shfl_xor(v, o);
        if ((t & 63) == 0) red[t >> 6] = v;
        __syncthreads();
        if (t == 0) flag[0] = ((red[0] | red[1] | red[2] | red[3]) == 0) ? 1 : 0;
    }
}

// degree over dst; require BOTH endpoints valid so fill_csr fills every slot
__global__ void degree_kernel(const void* __restrict__ ei, const int* __restrict__ flag,
                              int* __restrict__ deg) {
    int i = blockIdx.x * blockDim.x + threadIdx.x;
    if (i >= EDGES) return;
    int f = flag[0];
    int s = idx_at(ei, i, f), d = idx_at(ei, EDGES + i, f);
    if ((unsigned)s < NODES && (unsigned)d < NODES) atomicAdd(&deg[d], 1);
}

// fused: dinv1/dinv2 + xs = bf16(x * dinv1)
__global__ void dinv_prescale(const int* __restrict__ deg, const float* __restrict__ x,
                              float* __restrict__ dinv1, float* __restrict__ dinv2,
                              bf16* __restrict__ xs) {
    int wave = threadIdx.x >> 6, lane = threadIdx.x & 63;
    int row = blockIdx.x * 4 + wave;
    if (row >= NODES) return;
    float cdeg = (float)deg[row];
    float d1 = 1.0f / sqrtf(cdeg + 2.0f);
    float d2 = 1.0f / sqrtf(cdeg + 1.0f);
    if (lane == 0) { dinv1[row] = d1; dinv2[row] = d2; }
    xs[(size_t)row * 64 + lane] = __float2bfloat16(x[(size_t)row * 64 + lane] * d1);
}

// ---- exclusive scan of deg -> row_ptr (+ cursor copy) ----
__global__ void scanA(const int* __restrict__ deg, int* __restrict__ blocksum) {
    __shared__ int red[4];
    int b = blockIdx.x, t = threadIdx.x;
    int base = b * 1024;
    int s = 0;
#pragma unroll
    for (int k = 0; k < 4; ++k) {
        int i = base + t + k * 256;
        if (i < NODES) s += deg[i];
    }
    for (int o = 32; o; o >>= 1) s += __shfl_xor(s, o);
    if ((t & 63) == 0) red[t >> 6] = s;
    __syncthreads();
    if (t == 0) blocksum[b] = red[0] + red[1] + red[2] + red[3];
}

__global__ void scanB(const int* __restrict__ blocksum, int* __restrict__ blockoff) {
    __shared__ int sc[128];
    int t = threadIdx.x;
    int v = (t < NTILES) ? blocksum[t] : 0;
    sc[t] = v;
    __syncthreads();
    for (int o = 1; o < 128; o <<= 1) {
        int u = (t >= o) ? sc[t - o] : 0;
        __syncthreads();
        sc[t] += u;
        __syncthreads();
    }
    if (t < NTILES) blockoff[t] = sc[t] - v;  // exclusive
}

__global__ void scanC(const int* __restrict__ deg, const int* __restrict__ blockoff,
                      int* __restrict__ row_ptr, int* __restrict__ cursor) {
    __shared__ int sc[256];
    int b = blockIdx.x, t = threadIdx.x;
    int base = b * 1024 + t * 4;
    int v[4];
#pragma unroll
    for (int k = 0; k < 4; ++k) {
        int i = base + k;
        v[k] = (i < NODES) ? deg[i] : 0;
    }
    int tsum = v[0] + v[1] + v[2] + v[3];
    sc[t] = tsum;
    __syncthreads();
    for (int o = 1; o < 256; o <<= 1) {
        int u = (t >= o) ? sc[t - o] : 0;
        __syncthreads();
        sc[t] += u;
        __syncthreads();
    }
    int excl = sc[t] - tsum + blockoff[b];
#pragma unroll
    for (int k = 0; k < 4; ++k) {
        int i = base + k;
        if (i <= NODES) row_ptr[i] = excl;
        if (i < NODES) cursor[i] = excl;
        excl += v[k];
    }
}
// ----------------------------------------------------------

__global__ void fill_csr(const void* __restrict__ ei, const int* __restrict__ flag,
                         int* __restrict__ cursor, int* __restrict__ csr_src) {
    int i = blockIdx.x * blockDim.x + threadIdx.x;
    if (i >= EDGES) return;
    int f = flag[0];
    int s = idx_at(ei, i, f), d = idx_at(ei, EDGES + i, f);
    if ((unsigned)s >= NODES || (unsigned)d >= NODES) return;
    int slot = atomicAdd(&cursor[d], 1);  // cursor pre-seeded with row_ptr
    csr_src[slot] = s;
}

// quad-edge gather: quarter q=lane>>4 covers edge j+q; c=lane&15 covers an
// 8-byte chunk (4 bf16 columns). One uint2 wave-load = 4 full source rows.
// All state in scalars (round-9 spill lesson). Returns per-lane sums for
// columns 4c..4c+3, replicated across quarters.
__device__ __forceinline__ void gather_quad(const uint2* __restrict__ feat4,
                                            const int* __restrict__ csr, int beg, int end,
                                            int lane, float& ox, float& oy, float& oz,
                                            float& ow) {
    int q = lane >> 4, c = lane & 15;
    float ax = 0, ay = 0, az = 0, aw = 0;
    float bx = 0, by = 0, bz = 0, bw = 0;
    for (int cb = beg; cb < end; cb += 64) {
        int cnt = min(64, end - cb);
        int idx = (cb + lane < end) ? csr[cb + lane] : 0;
        for (int j = 0; j < cnt; j += 8) {
            int e0 = j + q, e1 = j + 4 + q;
            int s0 = __shfl(idx, e0);
            uint2 u0 = feat4[(size_t)s0 * 16 + c];
            if (e0 < cnt) {
                ax += __uint_as_float(u0.x << 16);
                ay += __uint_as_float(u0.x & 0xffff0000u);
                az += __uint_as_float(u0.y << 16);
                aw += __uint_as_float(u0.y & 0xffff0000u);
            }
            if (j + 4 < cnt) {  // wave-uniform
                int s1 = __shfl(idx, e1);
                uint2 u1 = feat4[(size_t)s1 * 16 + c];
                if (e1 < cnt) {
                    bx += __uint_as_float(u1.x << 16);
                    by += __uint_as_float(u1.x & 0xffff0000u);
                    bz += __uint_as_float(u1.y << 16);
                    bw += __uint_as_float(u1.y & 0xffff0000u);
                }
            }
        }
    }
    ax += bx; ay += by; az += bz; aw += bw;
    ax += __shfl_xor(ax, 16); ay += __shfl_xor(ay, 16);
    az += __shfl_xor(az, 16); aw += __shfl_xor(aw, 16);
    ax += __shfl_xor(ax, 32); ay += __shfl_xor(ay, 32);
    az += __shfl_xor(az, 32); aw += __shfl_xor(aw, 32);
    ox = ax; oy = ay; oz = az; ow = aw;
}

// GEMM from quad layout: lane cc in [0,16) holds sums for cols 4cc..4cc+3
__device__ __forceinline__ float quad_gemm(const float* __restrict__ Wl, float vx, float vy,
                                           float vz, float vw, float bias_l, int lane) {
    float a = bias_l;
#pragma unroll
    for (int cc = 0; cc < 16; ++cc) {
        float w0 = Wl[(4 * cc) * 64 + lane];
        float w1 = Wl[(4 * cc + 1) * 64 + lane];
        float w2 = Wl[(4 * cc + 2) * 64 + lane];
        float w3 = Wl[(4 * cc + 3) * 64 + lane];
        a += __shfl(vx, cc) * w0 + __shfl(vy, cc) * w1 + __shfl(vz, cc) * w2 +
             __shfl(vw, cc) * w3;
    }
    return a;
}

// fused layer1: gather(xs) + self*2 + @W1 + b1 + LN + leaky -> h1s = h1*dinv2
__global__ void gcn1_fused(const uint2* __restrict__ xs4, const int* __restrict__ csr,
                           const int* __restrict__ rp, const float* __restrict__ dinv1,
                           const float* __restrict__ dinv2, const float* __restrict__ W1,
                           const float* __restrict__ b1, const float* __restrict__ lng,
                           const float* __restrict__ lnb, bf16* __restrict__ h1s) {
    __shared__ float Wl[4096];
    int t = threadIdx.x;
    for (int i = t; i < 4096; i += 256) Wl[i] = W1[i];
    __syncthreads();
    int lane = t & 63, wave = t >> 6;
    int row = blockIdx.x * 4 + wave;
    if (row >= NODES) return;
    float vx, vy, vz, vw;
    gather_quad(xs4, csr, rp[row], rp[row + 1], lane, vx, vy, vz, vw);
    uint2 us = xs4[(size_t)row * 16 + (lane & 15)];
    float dv = dinv1[row];
    vx = dv * (vx + 2.0f * __uint_as_float(us.x << 16));
    vy = dv * (vy + 2.0f * __uint_as_float(us.x & 0xffff0000u));
    vz = dv * (vz + 2.0f * __uint_as_float(us.y << 16));
    vw = dv * (vw + 2.0f * __uint_as_float(us.y & 0xffff0000u));
    float a = quad_gemm(Wl, vx, vy, vz, vw, b1[lane], lane);
    float s = a;
    for (int o = 32; o; o >>= 1) s += __shfl_xor(s, o);
    float mu = s * (1.0f / 64.0f);
    float d = a - mu;
    float q = d * d;
    for (int o = 32; o; o >>= 1) q += __shfl_xor(q, o);
    float var = q * (1.0f / 64.0f);
    float y = d / sqrtf(var + 1e-5f) * lng[lane] + lnb[lane];
    h1s[(size_t)row * 64 + lane] = __float2bfloat16(lrelu(y) * dinv2[row]);
}

// fused layer2: gather(h1s) + self + @W2 + b2 + leaky + block-merged max-pool
__global__ void gcn2_fused(const uint2* __restrict__ h1s4, const int* __restrict__ csr,
                           const int* __restrict__ rp, const float* __restrict__ dinv2,
                           const float* __restrict__ W2, const float* __restrict__ b2,
                           const void* __restrict__ batch, const int* __restrict__ flag,
                           unsigned* __restrict__ pooled) {
    __shared__ float Wl[4096];
    __shared__ float ash[4][64];
    __shared__ int gsh[4];
    int t = threadIdx.x;
    for (int i = t; i < 4096; i += 256) Wl[i] = W2[i];
    __syncthreads();
    int lane = t & 63, wave = t >> 6;
    int row = blockIdx.x * 4 + wave;
    float a = -1e4f;
    int g = -1;
    if (row < NODES) {
        float vx, vy, vz, vw;
        gather_quad(h1s4, csr, rp[row], rp[row + 1], lane, vx, vy, vz, vw);
        uint2 us = h1s4[(size_t)row * 16 + (lane & 15)];
        float dv = dinv2[row];
        vx = dv * (vx + __uint_as_float(us.x << 16));
        vy = dv * (vy + __uint_as_float(us.x & 0xffff0000u));
        vz = dv * (vz + __uint_as_float(us.y << 16));
        vw = dv * (vw + __uint_as_float(us.y & 0xffff0000u));
        a = lrelu(quad_gemm(Wl, vx, vy, vz, vw, b2[lane], lane));
        g = idx_at(batch, row, flag[0]);
    }
    ash[wave][lane] = a;
    if (lane == 0) gsh[wave] = g;
    __syncthreads();
    if (wave == 0) {  // run-merge the block's 4 rows (batch sorted -> usually 1 graph)
        float m = ash[0][lane];
        int gc = gsh[0];
#pragma unroll
        for (int r = 1; r < 4; ++r) {
            int gr = gsh[r];
            float ar = ash[r][lane];
            if (gr == gc) {
                m = fmaxf(m, ar);
            } else {
                if ((unsigned)gc < NGRAPH) atomicMax(&pooled[gc * 64 + lane], mapf(m));
                gc = gr;
                m = ar;
            }
        }
        if ((unsigned)gc < NGRAPH) atomicMax(&pooled[gc * 64 + lane], mapf(m));
    }
}

// head: z = pooled@W3+b3; LN; leaky; z@W4+b4; softmax. One block per graph.
__global__ void head_kernel(const unsigned* __restrict__ pooled, const float* __restrict__ W3,
                            const float* __restrict__ b3, const float* __restrict__ g2,
                            const float* __restrict__ be2, const float* __restrict__ W4,
                            const float* __restrict__ b4, float* __restrict__ out) {
    __shared__ float prow[64];
    __shared__ float z[768];
    __shared__ float rs[4], rss[4];
    __shared__ float mu_s, rstd_s;
    __shared__ float red[10];
    int t = threadIdx.x, gI = blockIdx.x;
    if (t < 64) prow[t] = unmapf(pooled[gI * 64 + t]);
    __syncthreads();
    for (int c = t; c < 768; c += 256) {
        float acc = b3[c];
#pragma unroll 16
        for (int k = 0; k < 64; ++k) acc += prow[k] * W3[k * 768 + c];
        z[c] = acc;
    }
    __syncthreads();
    float s = 0.0f, ss = 0.0f;
    for (int c = t; c < 768; c += 256) {
        float v = z[c];
        s += v;
        ss += v * v;
    }
    for (int o = 32; o; o >>= 1) {
        s += __shfl_xor(s, o);
        ss += __shfl_xor(ss, o);
    }
    if ((t & 63) == 0) { rs[t >> 6] = s; rss[t >> 6] = ss; }
    __syncthreads();
    if (t == 0) {
        float S = rs[0] + rs[1] + rs[2] + rs[3];
        float SS = rss[0] + rss[1] + rss[2] + rss[3];
        float mu = S * (1.0f / 768.0f);
        float var = SS * (1.0f / 768.0f) - mu * mu;
        mu_s = mu;
        rstd_s = 1.0f / sqrtf(fmaxf(var, 0.0f) + 1e-5f);
    }
    __syncthreads();
    for (int c = t; c < 768; c += 256) {
        float y = (z[c] - mu_s) * rstd_s * g2[c] + be2[c];
        z[c] = lrelu(y);
    }
    if (t < 10) red[t] = 0.0f;
    __syncthreads();
    float p[10];
#pragma unroll
    for (int c = 0; c < 10; ++c) p[c] = 0.0f;
    for (int k = t; k < 768; k += 256) {
        float zv = z[k];
#pragma unroll
        for (int c = 0; c < 10; ++c) p[c] += zv * W4[k * 10 + c];
    }
#pragma unroll
    for (int c = 0; c < 10; ++c) atomicAdd(&red[c], p[c]);
    __syncthreads();
    if (t == 0) {
        float l[10], m = -1e30f;
#pragma unroll
        for (int c = 0; c < 10; ++c) {
            l[c] = red[c] + b4[c];
            m = fmaxf(m, l[c]);
        }
        float sum = 0.0f;
#pragma unroll
        for (int c = 0; c < 10; ++c) {
            l[c] = expf(l[c] - m);
            sum += l[c];
        }
        float inv = 1.0f / sum;
#pragma unroll
        for (int c = 0; c < 10; ++c) out[gI * 10 + c] = l[c] * inv;
    }
}

extern "C" void kernel_launch(void* const* d_in, const int* in_sizes, int n_in,
                              void* d_out, int out_size, void* d_ws, size_t ws_size,
                              hipStream_t stream) {
    const size_t REQUIRED = (size_t)NODES * 64 * 2 * 2  // xs + h1s (bf16)
                          + (size_t)EDGES * 4           // csr_src
                          + (size_t)(NODES + 1) * 4     // row_ptr
                          + (size_t)NODES * 4 * 4       // cursor, deg, dinv1, dinv2
                          + (size_t)NTILES * 4 * 2      // blocksum, blockoff
                          + (size_t)NGRAPH * 64 * 4     // pooled
                          + 16;                         // flag
    if (ws_size < REQUIRED) {
        sentinel_kernel<<<20, 256, 0, stream>>>((float*)d_out, 64.0f);
        return;
    }

    const float* x = (const float*)d_in[0];
    const void* ei = d_in[1];
    const void* batch = d_in[2];
    const float* W1 = (const float*)d_in[3];
    const float* b1 = (const float*)d_in[4];
    const float* lng = (const float*)d_in[5];
    const float* lnb = (const float*)d_in[6];
    const float* W2 = (const float*)d_in[7];
    const float* b2 = (const float*)d_in[8];
    const float* W3 = (const float*)d_in[9];
    const float* b3 = (const float*)d_in[10];
    const float* g2 = (const float*)d_in[11];
    const float* be2 = (const float*)d_in[12];
    const float* W4 = (const float*)d_in[13];
    const float* b4 = (const float*)d_in[14];

    bf16* xs = (bf16*)d_ws;                               // N*64 bf16
    bf16* h1s = xs + (size_t)NODES * 64;                  // N*64 bf16
    int* csr_src = (int*)(h1s + (size_t)NODES * 64);      // E
    int* row_ptr = csr_src + EDGES;                       // N+1
    int* cursor = row_ptr + (NODES + 1);                  // N
    int* deg = cursor + NODES;                            // N
    float* dinv1 = (float*)(deg + NODES);                 // N
    float* dinv2 = dinv1 + NODES;                         // N
    int* blocksum = (int*)(dinv2 + NODES);                // NTILES
    int* blockoff = blocksum + NTILES;                    // NTILES
    unsigned* pooled = (unsigned*)(blockoff + NTILES);    // G*64
    int* flag = (int*)(pooled + NGRAPH * 64);             // 1

    detect_init<<<(NODES + 255) / 256, 256, 0, stream>>>((const int*)ei, flag, deg, pooled);

    // CSR build
    degree_kernel<<<(EDGES + 255) / 256, 256, 0, stream>>>(ei, flag, deg);
    dinv_prescale<<<(NODES + 3) / 4, 256, 0, stream>>>(deg, x, dinv1, dinv2, xs);
    scanA<<<NTILES, 256, 0, stream>>>(deg, blocksum);
    scanB<<<1, 128, 0, stream>>>(blocksum, blockoff);
    scanC<<<NTILES, 256, 0, stream>>>(deg, blockoff, row_ptr, cursor);
    fill_csr<<<(EDGES + 255) / 256, 256, 0, stream>>>(ei, flag, cursor, csr_src);

    // fused layers: 4 waves/block, 1 row/wave
    gcn1_fused<<<(NODES + 3) / 4, 256, 0, stream>>>((const uint2*)xs, csr_src, row_ptr,
                                                    dinv1, dinv2, W1, b1, lng, lnb, h1s);
    gcn2_fused<<<(NODES + 3) / 4, 256, 0, stream>>>((const uint2*)h1s, csr_src, row_ptr,
                                                    dinv2, W2, b2, batch, flag, pooled);

    // head
    head_kernel<<<NGRAPH, 256, 0, stream>>>(pooled, W3, b3, g2, be2, W4, b4, (float*)d_out);
}

// Round 11
// 449.315 us; speedup vs baseline: 4.2273x; 1.3469x over previous
//
#include <hip/hip_runtime.h>
#include <hip/hip_bf16.h>

#define NODES 100000
#define EDGES 1600000
#define NGRAPH 512
#define NTILES 98   // ceil(100001 / 1024)
#define VSS 72      // LDS row stride in shorts (144 B = 9*16B, conflict-free b128)

using bf16 = __hip_bfloat16;
typedef long long ll;
using frag8 = __attribute__((ext_vector_type(8))) short;  // 8 bf16 (4 VGPRs)
using f32x4 = __attribute__((ext_vector_type(4))) float;

__device__ __forceinline__ float lrelu(float v) { return v > 0.0f ? v : 0.2f * v; }

__device__ __forceinline__ unsigned mapf(float f) {
    unsigned u = __float_as_uint(f);
    return (u & 0x80000000u) ? ~u : (u | 0x80000000u);
}
__device__ __forceinline__ float unmapf(unsigned u) {
    return __uint_as_float((u & 0x80000000u) ? (u ^ 0x80000000u) : ~u);
}

__device__ __forceinline__ int idx_at(const void* raw, int i, int f) {
    return f ? (int)((const ll*)raw)[i] : ((const int*)raw)[i];
}

__device__ __forceinline__ unsigned short tobf(float f) {
    bf16 h = __float2bfloat16(f);
    return *reinterpret_cast<unsigned short*>(&h);
}

__global__ void sentinel_kernel(float* out, float v) {
    int i = blockIdx.x * blockDim.x + threadIdx.x;
    if (i < NGRAPH * 10) out[i] = v;
}

// fused: int64-detect (block 0) + deg=0 + pooled=sentinel
__global__ void detect_init(const int* __restrict__ w, int* __restrict__ flag,
                            int* __restrict__ deg, unsigned* __restrict__ pooled) {
    int i = blockIdx.x * blockDim.x + threadIdx.x;
    if (i < NODES) deg[i] = 0;
    if (i < NGRAPH * 64) pooled[i] = mapf(-1e4f);
    if (blockIdx.x == 0) {
        __shared__ int red[4];
        int t = threadIdx.x;
        int v = 0;
        for (int k = t; k < 4096; k += 256) v |= w[2 * k + 1];
        for (int o = 32; o; o >>= 1) v |= __shfl_xor(v, o);
        if ((t & 63) == 0) red[t >> 6] = v;
        __syncthreads();
        if (t == 0) flag[0] = ((red[0] | red[1] | red[2] | red[3]) == 0) ? 1 : 0;
    }
}

// degree over dst, 2 edges/thread; require BOTH endpoints valid
__global__ void degree_kernel(const void* __restrict__ ei, const int* __restrict__ flag,
                              int* __restrict__ deg) {
    int i = (blockIdx.x * blockDim.x + threadIdx.x) * 2;
    if (i >= EDGES) return;
    int f = flag[0];
    int s0 = idx_at(ei, i, f), d0 = idx_at(ei, EDGES + i, f);
    int s1 = idx_at(ei, i + 1, f), d1 = idx_at(ei, EDGES + i + 1, f);
    if ((unsigned)s0 < NODES && (unsigned)d0 < NODES) atomicAdd(&deg[d0], 1);
    if ((unsigned)s1 < NODES && (unsigned)d1 < NODES) atomicAdd(&deg[d1], 1);
}

// fused: dinv1/dinv2 + xs = bf16(x * dinv1)
__global__ void dinv_prescale(const int* __restrict__ deg, const float* __restrict__ x,
                              float* __restrict__ dinv1, float* __restrict__ dinv2,
                              bf16* __restrict__ xs) {
    int wave = threadIdx.x >> 6, lane = threadIdx.x & 63;
    int row = blockIdx.x * 4 + wave;
    if (row >= NODES) return;
    float cdeg = (float)deg[row];
    float d1 = 1.0f / sqrtf(cdeg + 2.0f);
    float d2 = 1.0f / sqrtf(cdeg + 1.0f);
    if (lane == 0) { dinv1[row] = d1; dinv2[row] = d2; }
    xs[(size_t)row * 64 + lane] = __float2bfloat16(x[(size_t)row * 64 + lane] * d1);
}

// ---- exclusive scan of deg -> row_ptr (+ cursor copy) ----
__global__ void scanA(const int* __restrict__ deg, int* __restrict__ blocksum) {
    __shared__ int red[4];
    int b = blockIdx.x, t = threadIdx.x;
    int base = b * 1024;
    int s = 0;
#pragma unroll
    for (int k = 0; k < 4; ++k) {
        int i = base + t + k * 256;
        if (i < NODES) s += deg[i];
    }
    for (int o = 32; o; o >>= 1) s += __shfl_xor(s, o);
    if ((t & 63) == 0) red[t >> 6] = s;
    __syncthreads();
    if (t == 0) blocksum[b] = red[0] + red[1] + red[2] + red[3];
}

__global__ void scanB(const int* __restrict__ blocksum, int* __restrict__ blockoff) {
    __shared__ int sc[128];
    int t = threadIdx.x;
    int v = (t < NTILES) ? blocksum[t] : 0;
    sc[t] = v;
    __syncthreads();
    for (int o = 1; o < 128; o <<= 1) {
        int u = (t >= o) ? sc[t - o] : 0;
        __syncthreads();
        sc[t] += u;
        __syncthreads();
    }
    if (t < NTILES) blockoff[t] = sc[t] - v;  // exclusive
}

__global__ void scanC(const int* __restrict__ deg, const int* __restrict__ blockoff,
                      int* __restrict__ row_ptr, int* __restrict__ cursor) {
    __shared__ int sc[256];
    int b = blockIdx.x, t = threadIdx.x;
    int base = b * 1024 + t * 4;
    int v[4];
#pragma unroll
    for (int k = 0; k < 4; ++k) {
        int i = base + k;
        v[k] = (i < NODES) ? deg[i] : 0;
    }
    int tsum = v[0] + v[1] + v[2] + v[3];
    sc[t] = tsum;
    __syncthreads();
    for (int o = 1; o < 256; o <<= 1) {
        int u = (t >= o) ? sc[t - o] : 0;
        __syncthreads();
        sc[t] += u;
        __syncthreads();
    }
    int excl = sc[t] - tsum + blockoff[b];
#pragma unroll
    for (int k = 0; k < 4; ++k) {
        int i = base + k;
        if (i <= NODES) row_ptr[i] = excl;
        if (i < NODES) cursor[i] = excl;
        excl += v[k];
    }
}
// ----------------------------------------------------------

__global__ void fill_csr(const void* __restrict__ ei, const int* __restrict__ flag,
                         int* __restrict__ cursor, int* __restrict__ csr_src) {
    int i = (blockIdx.x * blockDim.x + threadIdx.x) * 2;
    if (i >= EDGES) return;
    int f = flag[0];
    int s0 = idx_at(ei, i, f), d0 = idx_at(ei, EDGES + i, f);
    int s1 = idx_at(ei, i + 1, f), d1 = idx_at(ei, EDGES + i + 1, f);
    if ((unsigned)s0 < NODES && (unsigned)d0 < NODES) csr_src[atomicAdd(&cursor[d0], 1)] = s0;
    if ((unsigned)s1 < NODES && (unsigned)d1 < NODES) csr_src[atomicAdd(&cursor[d1], 1)] = s1;
}

// quad-edge gather (round-10 proven): q=lane>>4 covers edge j+q; c=lane&15 covers
// an 8-byte chunk (4 bf16 cols). All state scalars. Sums replicated over quarters.
__device__ __forceinline__ void gather_quad(const uint2* __restrict__ feat4,
                                            const int* __restrict__ csr, int beg, int end,
                                            int lane, float& ox, float& oy, float& oz,
                                            float& ow) {
    int q = lane >> 4, c = lane & 15;
    float ax = 0, ay = 0, az = 0, aw = 0;
    float bx = 0, by = 0, bz = 0, bw = 0;
    for (int cb = beg; cb < end; cb += 64) {
        int cnt = min(64, end - cb);
        int idx = (cb + lane < end) ? csr[cb + lane] : 0;
        for (int j = 0; j < cnt; j += 8) {
            int e0 = j + q, e1 = j + 4 + q;
            int s0 = __shfl(idx, e0);
            uint2 u0 = feat4[(size_t)s0 * 16 + c];
            if (e0 < cnt) {
                ax += __uint_as_float(u0.x << 16);
                ay += __uint_as_float(u0.x & 0xffff0000u);
                az += __uint_as_float(u0.y << 16);
                aw += __uint_as_float(u0.y & 0xffff0000u);
            }
            if (j + 4 < cnt) {
                int s1 = __shfl(idx, e1);
                uint2 u1 = feat4[(size_t)s1 * 16 + c];
                if (e1 < cnt) {
                    bx += __uint_as_float(u1.x << 16);
                    by += __uint_as_float(u1.x & 0xffff0000u);
                    bz += __uint_as_float(u1.y << 16);
                    bw += __uint_as_float(u1.y & 0xffff0000u);
                }
            }
        }
    }
    ax += bx; ay += by; az += bz; aw += bw;
    ax += __shfl_xor(ax, 16); ay += __shfl_xor(ay, 16);
    az += __shfl_xor(az, 16); aw += __shfl_xor(aw, 16);
    ax += __shfl_xor(ax, 32); ay += __shfl_xor(ay, 32);
    az += __shfl_xor(az, 32); aw += __shfl_xor(aw, 32);
    ox = ax; oy = ay; oz = az; ow = aw;
}

// shared body: stage W^T, gather 16 rows/wave into Vs (bf16), MFMA V@W.
// Returns acc[nt] (C/D layout: col=lane&15, row=quad*4+reg) for the wave's 16 rows.
__device__ __forceinline__ void gcn_core(const uint2* __restrict__ feat4,
                                         const int* __restrict__ csr,
                                         const int* __restrict__ rp,
                                         const float* __restrict__ dinv, float selfw,
                                         const float* __restrict__ W, short* Vs, short* Wt,
                                         int rowBase, int lane, int wave, f32x4 (&acc)[4]) {
    int t = wave * 64 + lane;
    for (int i = t; i < 4096; i += 256) {  // Wt[n][k] = W[k][n], bf16
        int k = i >> 6, n = i & 63;
        Wt[n * VSS + k] = (short)tobf(W[i]);
    }
    __syncthreads();
    int myBase = rowBase + wave * 16;
    int rpv = (lane < 17) ? rp[min(myBase + lane, NODES)] : 0;
    int c = lane & 15;
    for (int i = 0; i < 16; ++i) {
        int beg = __shfl(rpv, i), end = __shfl(rpv, i + 1);
        float vx, vy, vz, vw;
        gather_quad(feat4, csr, beg, end, lane, vx, vy, vz, vw);
        int row = myBase + i;
        float dv = 0.0f;
        uint2 us = make_uint2(0u, 0u);
        if (row < NODES) {
            dv = dinv[row];
            us = feat4[(size_t)row * 16 + c];
        }
        vx = dv * (vx + selfw * __uint_as_float(us.x << 16));
        vy = dv * (vy + selfw * __uint_as_float(us.x & 0xffff0000u));
        vz = dv * (vz + selfw * __uint_as_float(us.y << 16));
        vw = dv * (vw + selfw * __uint_as_float(us.y & 0xffff0000u));
        if (lane < 16) {
            uint2 p;
            p.x = (unsigned)tobf(vx) | ((unsigned)tobf(vy) << 16);
            p.y = (unsigned)tobf(vz) | ((unsigned)tobf(vw) << 16);
            *(uint2*)(Vs + (size_t)(wave * 16 + i) * VSS + c * 4) = p;
        }
    }
    // MFMA: A = Vs rows [wave*16, +16), B = Wt. K=64 in 2 steps.
    frag8 afr[2];
    int m = lane & 15, q = lane >> 4;
#pragma unroll
    for (int ks = 0; ks < 2; ++ks)
        afr[ks] = *(frag8*)(Vs + (size_t)(wave * 16 + m) * VSS + q * 8 + ks * 32);
#pragma unroll
    for (int nt = 0; nt < 4; ++nt) {
        f32x4 a = {0.f, 0.f, 0.f, 0.f};
#pragma unroll
        for (int ks = 0; ks < 2; ++ks) {
            frag8 bfr = *(frag8*)(Wt + (size_t)(nt * 16 + m) * VSS + q * 8 + ks * 32);
            a = __builtin_amdgcn_mfma_f32_16x16x32_bf16(afr[ks], bfr, a, 0, 0, 0);
        }
        acc[nt] = a;
    }
}

// layer1: gather + MFMA + bias + LN + leaky -> h1s = h1*dinv2 (bf16)
__global__ void __launch_bounds__(256, 2)
gcn1_fused(const uint2* __restrict__ xs4, const int* __restrict__ csr,
           const int* __restrict__ rp, const float* __restrict__ dinv1,
           const float* __restrict__ dinv2, const float* __restrict__ W1,
           const float* __restrict__ b1, const float* __restrict__ lng,
           const float* __restrict__ lnb, bf16* __restrict__ h1s) {
    __shared__ short sm[2 * 64 * VSS];
    short* Vs = sm;
    short* Wt = sm + 64 * VSS;
    int lane = threadIdx.x & 63, wave = threadIdx.x >> 6;
    int rowBase = blockIdx.x * 64;
    f32x4 acc[4];
    gcn_core(xs4, csr, rp, dinv1, 2.0f, W1, Vs, Wt, rowBase, lane, wave, acc);
    int c = lane & 15, q = lane >> 4;
    float bc[4], lg[4], lb[4];
#pragma unroll
    for (int nt = 0; nt < 4; ++nt) {
        bc[nt] = b1[nt * 16 + c];
        lg[nt] = lng[nt * 16 + c];
        lb[nt] = lnb[nt * 16 + c];
    }
#pragma unroll
    for (int r = 0; r < 4; ++r) {
        int grow = rowBase + wave * 16 + q * 4 + r;
        float v0 = acc[0][r] + bc[0], v1 = acc[1][r] + bc[1];
        float v2 = acc[2][r] + bc[2], v3 = acc[3][r] + bc[3];
        float s = v0 + v1 + v2 + v3;
        for (int o = 1; o < 16; o <<= 1) s += __shfl_xor(s, o);
        float mu = s * (1.0f / 64.0f);
        float d0 = v0 - mu, d1 = v1 - mu, d2 = v2 - mu, d3 = v3 - mu;
        float qq = d0 * d0 + d1 * d1 + d2 * d2 + d3 * d3;
        for (int o = 1; o < 16; o <<= 1) qq += __shfl_xor(qq, o);
        float rstd = 1.0f / sqrtf(qq * (1.0f / 64.0f) + 1e-5f);
        if (grow < NODES) {
            float d2v = dinv2[grow];
            bf16* dst = h1s + (size_t)grow * 64 + c;
            dst[0]  = __float2bfloat16(lrelu(d0 * rstd * lg[0] + lb[0]) * d2v);
            dst[16] = __float2bfloat16(lrelu(d1 * rstd * lg[1] + lb[1]) * d2v);
            dst[32] = __float2bfloat16(lrelu(d2 * rstd * lg[2] + lb[2]) * d2v);
            dst[48] = __float2bfloat16(lrelu(d3 * rstd * lg[3] + lb[3]) * d2v);
        }
    }
}

// layer2: gather + MFMA + bias + leaky + run-merged max-pool
__global__ void __launch_bounds__(256, 2)
gcn2_fused(const uint2* __restrict__ h1s4, const int* __restrict__ csr,
           const int* __restrict__ rp, const float* __restrict__ dinv2,
           const float* __restrict__ W2, const float* __restrict__ b2,
           const void* __restrict__ batch, const int* __restrict__ flag,
           unsigned* __restrict__ pooled) {
    __shared__ short sm[2 * 64 * VSS];
    __shared__ int gsh[64];
    short* Vs = sm;
    short* Wt = sm + 64 * VSS;
    int t = threadIdx.x, lane = t & 63, wave = t >> 6;
    int rowBase = blockIdx.x * 64;
    if (t < 64) {
        int row = rowBase + t;
        gsh[t] = (row < NODES) ? idx_at(batch, row, flag[0]) : -1;
    }
    f32x4 acc[4];
    gcn_core(h1s4, csr, rp, dinv2, 1.0f, W2, Vs, Wt, rowBase, lane, wave, acc);
    int c = lane & 15, q = lane >> 4;
    float bc[4];
#pragma unroll
    for (int nt = 0; nt < 4; ++nt) bc[nt] = b2[nt * 16 + c];
    __syncthreads();  // all waves done reading Vs/Wt before P overwrite
    float* P = (float*)sm;  // 64 x 65 fp32 pool buffer (fits in 18432 B)
#pragma unroll
    for (int r = 0; r < 4; ++r) {
        int mloc = wave * 16 + q * 4 + r;
#pragma unroll
        for (int nt = 0; nt < 4; ++nt)
            P[(size_t)mloc * 65 + nt * 16 + c] = lrelu(acc[nt][r] + bc[nt]);
    }
    __syncthreads();
    if (wave == 0) {  // run-merge 64 rows (batch sorted)
        float m = P[lane];
        int gc = gsh[0];
        for (int r = 1; r < 64; ++r) {
            int gr = gsh[r];
            float ar = P[(size_t)r * 65 + lane];
            if (gr == gc) {
                m = fmaxf(m, ar);
            } else {
                if ((unsigned)gc < NGRAPH) atomicMax(&pooled[gc * 64 + lane], mapf(m));
                gc = gr;
                m = ar;
            }
        }
        if ((unsigned)gc < NGRAPH) atomicMax(&pooled[gc * 64 + lane], mapf(m));
    }
}

// head: z = pooled@W3+b3; LN; leaky; z@W4+b4; softmax. One block per graph.
__global__ void head_kernel(const unsigned* __restrict__ pooled, const float* __restrict__ W3,
                            const float* __restrict__ b3, const float* __restrict__ g2,
                            const float* __restrict__ be2, const float* __restrict__ W4,
                            const float* __restrict__ b4, float* __restrict__ out) {
    __shared__ float prow[64];
    __shared__ float z[768];
    __shared__ float rs[4], rss[4];
    __shared__ float mu_s, rstd_s;
    __shared__ float red[10];
    int t = threadIdx.x, gI = blockIdx.x;
    if (t < 64) prow[t] = unmapf(pooled[gI * 64 + t]);
    __syncthreads();
    for (int c = t; c < 768; c += 256) {
        float acc = b3[c];
#pragma unroll 16
        for (int k = 0; k < 64; ++k) acc += prow[k] * W3[k * 768 + c];
        z[c] = acc;
    }
    __syncthreads();
    float s = 0.0f, ss = 0.0f;
    for (int c = t; c < 768; c += 256) {
        float v = z[c];
        s += v;
        ss += v * v;
    }
    for (int o = 32; o; o >>= 1) {
        s += __shfl_xor(s, o);
        ss += __shfl_xor(ss, o);
    }
    if ((t & 63) == 0) { rs[t >> 6] = s; rss[t >> 6] = ss; }
    __syncthreads();
    if (t == 0) {
        float S = rs[0] + rs[1] + rs[2] + rs[3];
        float SS = rss[0] + rss[1] + rss[2] + rss[3];
        float mu = S * (1.0f / 768.0f);
        float var = SS * (1.0f / 768.0f) - mu * mu;
        mu_s = mu;
        rstd_s = 1.0f / sqrtf(fmaxf(var, 0.0f) + 1e-5f);
    }
    __syncthreads();
    for (int c = t; c < 768; c += 256) {
        float y = (z[c] - mu_s) * rstd_s * g2[c] + be2[c];
        z[c] = lrelu(y);
    }
    if (t < 10) red[t] = 0.0f;
    __syncthreads();
    float p[10];
#pragma unroll
    for (int c = 0; c < 10; ++c) p[c] = 0.0f;
    for (int k = t; k < 768; k += 256) {
        float zv = z[k];
#pragma unroll
        for (int c = 0; c < 10; ++c) p[c] += zv * W4[k * 10 + c];
    }
#pragma unroll
    for (int c = 0; c < 10; ++c) atomicAdd(&red[c], p[c]);
    __syncthreads();
    if (t == 0) {
        float l[10], m = -1e30f;
#pragma unroll
        for (int c = 0; c < 10; ++c) {
            l[c] = red[c] + b4[c];
            m = fmaxf(m, l[c]);
        }
        float sum = 0.0f;
#pragma unroll
        for (int c = 0; c < 10; ++c) {
            l[c] = expf(l[c] - m);
            sum += l[c];
        }
        float inv = 1.0f / sum;
#pragma unroll
        for (int c = 0; c < 10; ++c) out[gI * 10 + c] = l[c] * inv;
    }
}

extern "C" void kernel_launch(void* const* d_in, const int* in_sizes, int n_in,
                              void* d_out, int out_size, void* d_ws, size_t ws_size,
                              hipStream_t stream) {
    const size_t REQUIRED = (size_t)NODES * 64 * 2 * 2  // xs + h1s (bf16)
                          + (size_t)EDGES * 4           // csr_src
                          + (size_t)(NODES + 1) * 4     // row_ptr
                          + (size_t)NODES * 4 * 4       // cursor, deg, dinv1, dinv2
                          + (size_t)NTILES * 4 * 2      // blocksum, blockoff
                          + (size_t)NGRAPH * 64 * 4     // pooled
                          + 16;                         // flag
    if (ws_size < REQUIRED) {
        sentinel_kernel<<<20, 256, 0, stream>>>((float*)d_out, 64.0f);
        return;
    }

    const float* x = (const float*)d_in[0];
    const void* ei = d_in[1];
    const void* batch = d_in[2];
    const float* W1 = (const float*)d_in[3];
    const float* b1 = (const float*)d_in[4];
    const float* lng = (const float*)d_in[5];
    const float* lnb = (const float*)d_in[6];
    const float* W2 = (const float*)d_in[7];
    const float* b2 = (const float*)d_in[8];
    const float* W3 = (const float*)d_in[9];
    const float* b3 = (const float*)d_in[10];
    const float* g2 = (const float*)d_in[11];
    const float* be2 = (const float*)d_in[12];
    const float* W4 = (const float*)d_in[13];
    const float* b4 = (const float*)d_in[14];

    bf16* xs = (bf16*)d_ws;                               // N*64 bf16
    bf16* h1s = xs + (size_t)NODES * 64;                  // N*64 bf16
    int* csr_src = (int*)(h1s + (size_t)NODES * 64);      // E
    int* row_ptr = csr_src + EDGES;                       // N+1
    int* cursor = row_ptr + (NODES + 1);                  // N
    int* deg = cursor + NODES;                            // N
    float* dinv1 = (float*)(deg + NODES);                 // N
    float* dinv2 = dinv1 + NODES;                         // N
    int* blocksum = (int*)(dinv2 + NODES);                // NTILES
    int* blockoff = blocksum + NTILES;                    // NTILES
    unsigned* pooled = (unsigned*)(blockoff + NTILES);    // G*64
    int* flag = (int*)(pooled + NGRAPH * 64);             // 1

    detect_init<<<(NODES + 255) / 256, 256, 0, stream>>>((const int*)ei, flag, deg, pooled);

    // CSR build
    degree_kernel<<<(EDGES / 2 + 255) / 256, 256, 0, stream>>>(ei, flag, deg);
    dinv_prescale<<<(NODES + 3) / 4, 256, 0, stream>>>(deg, x, dinv1, dinv2, xs);
    scanA<<<NTILES, 256, 0, stream>>>(deg, blocksum);
    scanB<<<1, 128, 0, stream>>>(blocksum, blockoff);
    scanC<<<NTILES, 256, 0, stream>>>(deg, blockoff, row_ptr, cursor);
    fill_csr<<<(EDGES / 2 + 255) / 256, 256, 0, stream>>>(ei, flag, cursor, csr_src);

    // fused layers: 64 rows/block (4 waves x 16 rows), MFMA GEMM
    gcn1_fused<<<(NODES + 63) / 64, 256, 0, stream>>>((const uint2*)xs, csr_src, row_ptr,
                                                      dinv1, dinv2, W1, b1, lng, lnb, h1s);
    gcn2_fused<<<(NODES + 63) / 64, 256, 0, stream>>>((const uint2*)h1s, csr_src, row_ptr,
                                                      dinv2, W2, b2, batch, flag, pooled);

    // head
    head_kernel<<<NGRAPH, 256, 0, stream>>>(pooled, W3, b3, g2, be2, W4, b4, (float*)d_out);
}

// Round 12
// 330.049 us; speedup vs baseline: 5.7548x; 1.3614x over previous
//
#include <hip/hip_runtime.h>
#include <hip/hip_bf16.h>

#define NODES 100000
#define EDGES 1600000
#define NGRAPH 512
#define NBINS 98    // ceil(NODES / 1024)
#define CHUNK 4096  // edges per binPlace/binCount block
#define VSS 72      // LDS row stride in shorts (144 B, conflict-free b128)

using bf16 = __hip_bfloat16;
typedef long long ll;
using frag8 = __attribute__((ext_vector_type(8))) short;  // 8 bf16 (4 VGPRs)
using f32x4 = __attribute__((ext_vector_type(4))) float;

__device__ __forceinline__ float lrelu(float v) { return v > 0.0f ? v : 0.2f * v; }

__device__ __forceinline__ unsigned mapf(float f) {
    unsigned u = __float_as_uint(f);
    return (u & 0x80000000u) ? ~u : (u | 0x80000000u);
}
__device__ __forceinline__ float unmapf(unsigned u) {
    return __uint_as_float((u & 0x80000000u) ? (u ^ 0x80000000u) : ~u);
}

__device__ __forceinline__ int idx_at(const void* raw, int i, int f) {
    return f ? (int)((const ll*)raw)[i] : ((const int*)raw)[i];
}

__device__ __forceinline__ unsigned short tobf(float f) {
    bf16 h = __float2bfloat16(f);
    return *reinterpret_cast<unsigned short*>(&h);
}

__global__ void sentinel_kernel(float* out, float v) {
    int i = blockIdx.x * blockDim.x + threadIdx.x;
    if (i < NGRAPH * 10) out[i] = v;
}

// fused: int64-detect (block 0) + pooled=sentinel + bin counters = 0
__global__ void detect_init(const int* __restrict__ w, int* __restrict__ flag,
                            unsigned* __restrict__ pooled, int* __restrict__ binTotal,
                            int* __restrict__ binCursor) {
    int i = blockIdx.x * blockDim.x + threadIdx.x;
    if (i < NGRAPH * 64) pooled[i] = mapf(-1e4f);
    if (i < NBINS) { binTotal[i] = 0; binCursor[i] = 0; }
    if (blockIdx.x == 0) {
        __shared__ int red[4];
        int t = threadIdx.x;
        int v = 0;
        for (int k = t; k < 4096; k += 256) v |= w[2 * k + 1];
        for (int o = 32; o; o >>= 1) v |= __shfl_xor(v, o);
        if ((t & 63) == 0) red[t >> 6] = v;
        __syncthreads();
        if (t == 0) flag[0] = ((red[0] | red[1] | red[2] | red[3]) == 0) ? 1 : 0;
    }
}

// pass 1: per-chunk LDS histogram over 98 bins -> global binTotal
__global__ void binCount(const void* __restrict__ ei, const int* __restrict__ flag,
                         int* __restrict__ binTotal) {
    __shared__ int hist[NBINS];
    int t = threadIdx.x;
    if (t < NBINS) hist[t] = 0;
    __syncthreads();
    int e0 = blockIdx.x * CHUNK;
    int f = flag[0];
#pragma unroll
    for (int k = 0; k < CHUNK / 256; ++k) {
        int i = e0 + k * 256 + t;
        if (i < EDGES) {
            int s = idx_at(ei, i, f), d = idx_at(ei, EDGES + i, f);
            if ((unsigned)s < NODES && (unsigned)d < NODES) atomicAdd(&hist[d >> 10], 1);
        }
    }
    __syncthreads();
    if (t < NBINS && hist[t] > 0) atomicAdd(&binTotal[t], hist[t]);
}

// scan bins -> binStart[99]; also row_ptr[NODES] = total valid edges
__global__ void scan98(const int* __restrict__ binTotal, int* __restrict__ binStart,
                       int* __restrict__ row_ptr) {
    __shared__ int sc[128];
    int t = threadIdx.x;
    int v = (t < NBINS) ? binTotal[t] : 0;
    sc[t] = v;
    __syncthreads();
    for (int o = 1; o < 128; o <<= 1) {
        int u = (t >= o) ? sc[t - o] : 0;
        __syncthreads();
        sc[t] += u;
        __syncthreads();
    }
    if (t < NBINS) binStart[t] = sc[t] - v;
    if (t == NBINS - 1) {
        binStart[NBINS] = sc[t];
        row_ptr[NODES] = sc[t];
    }
}

// pass 2: stage chunk sorted-by-bin in LDS, copy out in contiguous runs.
// record = (src << 10) | (dst & 1023)  (src < 2^17 -> 27 bits)
__global__ void binPlace(const void* __restrict__ ei, const int* __restrict__ flag,
                         const int* __restrict__ binStart, int* __restrict__ binCursor,
                         unsigned* __restrict__ staging) {
    __shared__ unsigned recs[CHUNK];
    __shared__ unsigned char binsA[CHUNK];
    __shared__ int hist[NBINS], lstart[NBINS + 1], baseg[NBINS], lcur[NBINS];
    int t = threadIdx.x;
    if (t < NBINS) { hist[t] = 0; lcur[t] = 0; }
    __syncthreads();
    int e0 = blockIdx.x * CHUNK;
    int f = flag[0];
#pragma unroll
    for (int k = 0; k < CHUNK / 256; ++k) {
        int i = e0 + k * 256 + t;
        if (i < EDGES) {
            int s = idx_at(ei, i, f), d = idx_at(ei, EDGES + i, f);
            if ((unsigned)s < NODES && (unsigned)d < NODES) atomicAdd(&hist[d >> 10], 1);
        }
    }
    __syncthreads();
    if (t == 0) {
        int acc = 0;
        for (int b = 0; b < NBINS; ++b) {
            lstart[b] = acc;
            acc += hist[b];
        }
        lstart[NBINS] = acc;
    }
    __syncthreads();
    if (t < NBINS && hist[t] > 0) baseg[t] = atomicAdd(&binCursor[t], hist[t]);
    __syncthreads();
#pragma unroll
    for (int k = 0; k < CHUNK / 256; ++k) {
        int i = e0 + k * 256 + t;
        if (i < EDGES) {
            int s = idx_at(ei, i, f), d = idx_at(ei, EDGES + i, f);
            if ((unsigned)s < NODES && (unsigned)d < NODES) {
                int b = d >> 10;
                int p = lstart[b] + atomicAdd(&lcur[b], 1);
                recs[p] = ((unsigned)s << 10) | (unsigned)(d & 1023);
                binsA[p] = (unsigned char)b;
            }
        }
    }
    __syncthreads();
    int nv = lstart[NBINS];
    for (int p = t; p < nv; p += 256) {
        int b = binsA[p];
        staging[binStart[b] + baseg[b] + (p - lstart[b])] = recs[p];
    }
}

// pass 3: one block per bin. Local degree histogram + scan -> row_ptr, dinv1/2;
// scatter src into the bin's csr region (L2-resident 65 KB window).
__global__ void csr_finalize(const unsigned* __restrict__ staging,
                             const int* __restrict__ binStart, int* __restrict__ row_ptr,
                             float* __restrict__ dinv1, float* __restrict__ dinv2,
                             int* __restrict__ csr_src) {
    __shared__ int lhist[1024];
    __shared__ int sc[256];
    int b = blockIdx.x, t = threadIdx.x;
    int r0 = b << 10;
    int s0 = binStart[b], s1 = binStart[b + 1];
    for (int j = t; j < 1024; j += 256) lhist[j] = 0;
    __syncthreads();
    for (int p = s0 + t; p < s1; p += 256) atomicAdd(&lhist[staging[p] & 1023], 1);
    __syncthreads();
    int base = t * 4;
    int v0 = lhist[base], v1 = lhist[base + 1], v2 = lhist[base + 2], v3 = lhist[base + 3];
    int tsum = v0 + v1 + v2 + v3;
    sc[t] = tsum;
    __syncthreads();
    for (int o = 1; o < 256; o <<= 1) {
        int u = (t >= o) ? sc[t - o] : 0;
        __syncthreads();
        sc[t] += u;
        __syncthreads();
    }
    int excl = sc[t] - tsum;
    int vv0 = v0, vv1 = v1, vv2 = v2, vv3 = v3;
    int ex[4];
    ex[0] = excl;
    ex[1] = excl + vv0;
    ex[2] = ex[1] + vv1;
    ex[3] = ex[2] + vv2;
    int vvs[4] = {vv0, vv1, vv2, vv3};
#pragma unroll
    for (int k = 0; k < 4; ++k) {
        int j = base + k;
        int row = r0 + j;
        if (row < NODES) {
            row_ptr[row] = s0 + ex[k];
            float dg = (float)vvs[k];
            dinv1[row] = 1.0f / sqrtf(dg + 2.0f);
            dinv2[row] = 1.0f / sqrtf(dg + 1.0f);
        }
    }
    __syncthreads();
#pragma unroll
    for (int k = 0; k < 4; ++k) lhist[base + k] = ex[k];  // cursors
    __syncthreads();
    for (int p = s0 + t; p < s1; p += 256) {
        unsigned rec = staging[p];
        int dl = rec & 1023;
        int slot = atomicAdd(&lhist[dl], 1);
        csr_src[s0 + slot] = (int)(rec >> 10);
    }
}

// xs = bf16(x * dinv1)
__global__ void prescale_x(const float* __restrict__ x, const float* __restrict__ dinv1,
                           bf16* __restrict__ xs) {
    int i = blockIdx.x * blockDim.x + threadIdx.x;
    if (i < NODES * 64) xs[i] = __float2bfloat16(x[i] * dinv1[i >> 6]);
}

// quad-edge gather (round-10 proven): q=lane>>4 covers edge j+q; c=lane&15 covers
// an 8-byte chunk (4 bf16 cols). All state scalars. Sums replicated over quarters.
__device__ __forceinline__ void gather_quad(const uint2* __restrict__ feat4,
                                            const int* __restrict__ csr, int beg, int end,
                                            int lane, float& ox, float& oy, float& oz,
                                            float& ow) {
    int q = lane >> 4, c = lane & 15;
    float ax = 0, ay = 0, az = 0, aw = 0;
    float bx = 0, by = 0, bz = 0, bw = 0;
    for (int cb = beg; cb < end; cb += 64) {
        int cnt = min(64, end - cb);
        int idx = (cb + lane < end) ? csr[cb + lane] : 0;
        for (int j = 0; j < cnt; j += 8) {
            int e0 = j + q, e1 = j + 4 + q;
            int s0 = __shfl(idx, e0);
            uint2 u0 = feat4[(size_t)s0 * 16 + c];
            if (e0 < cnt) {
                ax += __uint_as_float(u0.x << 16);
                ay += __uint_as_float(u0.x & 0xffff0000u);
                az += __uint_as_float(u0.y << 16);
                aw += __uint_as_float(u0.y & 0xffff0000u);
            }
            if (j + 4 < cnt) {
                int s1 = __shfl(idx, e1);
                uint2 u1 = feat4[(size_t)s1 * 16 + c];
                if (e1 < cnt) {
                    bx += __uint_as_float(u1.x << 16);
                    by += __uint_as_float(u1.x & 0xffff0000u);
                    bz += __uint_as_float(u1.y << 16);
                    bw += __uint_as_float(u1.y & 0xffff0000u);
                }
            }
        }
    }
    ax += bx; ay += by; az += bz; aw += bw;
    ax += __shfl_xor(ax, 16); ay += __shfl_xor(ay, 16);
    az += __shfl_xor(az, 16); aw += __shfl_xor(aw, 16);
    ax += __shfl_xor(ax, 32); ay += __shfl_xor(ay, 32);
    az += __shfl_xor(az, 32); aw += __shfl_xor(aw, 32);
    ox = ax; oy = ay; oz = az; ow = aw;
}

// shared body: stage W^T, gather 16 rows/wave into Vs (bf16), MFMA V@W.
// acc[nt] C/D layout: col=lane&15, row=quad*4+reg (verified fragment maps).
__device__ __forceinline__ void gcn_core(const uint2* __restrict__ feat4,
                                         const int* __restrict__ csr,
                                         const int* __restrict__ rp,
                                         const float* __restrict__ dinv, float selfw,
                                         const float* __restrict__ W, short* Vs, short* Wt,
                                         int rowBase, int lane, int wave, f32x4 (&acc)[4]) {
    int t = wave * 64 + lane;
    for (int i = t; i < 4096; i += 256) {  // Wt[n][k] = W[k][n], bf16
        int k = i >> 6, n = i & 63;
        Wt[n * VSS + k] = (short)tobf(W[i]);
    }
    __syncthreads();
    int myBase = rowBase + wave * 16;
    int rpv = (lane < 17) ? rp[min(myBase + lane, NODES)] : 0;
    int c = lane & 15;
    for (int i = 0; i < 16; ++i) {
        int beg = __shfl(rpv, i), end = __shfl(rpv, i + 1);
        float vx, vy, vz, vw;
        gather_quad(feat4, csr, beg, end, lane, vx, vy, vz, vw);
        int row = myBase + i;
        float dv = 0.0f;
        uint2 us = make_uint2(0u, 0u);
        if (row < NODES) {
            dv = dinv[row];
            us = feat4[(size_t)row * 16 + c];
        }
        vx = dv * (vx + selfw * __uint_as_float(us.x << 16));
        vy = dv * (vy + selfw * __uint_as_float(us.x & 0xffff0000u));
        vz = dv * (vz + selfw * __uint_as_float(us.y << 16));
        vw = dv * (vw + selfw * __uint_as_float(us.y & 0xffff0000u));
        if (lane < 16) {
            uint2 p;
            p.x = (unsigned)tobf(vx) | ((unsigned)tobf(vy) << 16);
            p.y = (unsigned)tobf(vz) | ((unsigned)tobf(vw) << 16);
            *(uint2*)(Vs + (size_t)(wave * 16 + i) * VSS + c * 4) = p;
        }
    }
    frag8 afr[2];
    int m = lane & 15, q = lane >> 4;
#pragma unroll
    for (int ks = 0; ks < 2; ++ks)
        afr[ks] = *(frag8*)(Vs + (size_t)(wave * 16 + m) * VSS + q * 8 + ks * 32);
#pragma unroll
    for (int nt = 0; nt < 4; ++nt) {
        f32x4 a = {0.f, 0.f, 0.f, 0.f};
#pragma unroll
        for (int ks = 0; ks < 2; ++ks) {
            frag8 bfr = *(frag8*)(Wt + (size_t)(nt * 16 + m) * VSS + q * 8 + ks * 32);
            a = __builtin_amdgcn_mfma_f32_16x16x32_bf16(afr[ks], bfr, a, 0, 0, 0);
        }
        acc[nt] = a;
    }
}

// layer1: gather + MFMA + bias + LN + leaky -> h1s = h1*dinv2 (bf16)
__global__ void __launch_bounds__(256, 2)
gcn1_fused(const uint2* __restrict__ xs4, const int* __restrict__ csr,
           const int* __restrict__ rp, const float* __restrict__ dinv1,
           const float* __restrict__ dinv2, const float* __restrict__ W1,
           const float* __restrict__ b1, const float* __restrict__ lng,
           const float* __restrict__ lnb, bf16* __restrict__ h1s) {
    __shared__ short sm[2 * 64 * VSS];
    short* Vs = sm;
    short* Wt = sm + 64 * VSS;
    int lane = threadIdx.x & 63, wave = threadIdx.x >> 6;
    int rowBase = blockIdx.x * 64;
    f32x4 acc[4];
    gcn_core(xs4, csr, rp, dinv1, 2.0f, W1, Vs, Wt, rowBase, lane, wave, acc);
    int c = lane & 15, q = lane >> 4;
    float bc[4], lg[4], lb[4];
#pragma unroll
    for (int nt = 0; nt < 4; ++nt) {
        bc[nt] = b1[nt * 16 + c];
        lg[nt] = lng[nt * 16 + c];
        lb[nt] = lnb[nt * 16 + c];
    }
#pragma unroll
    for (int r = 0; r < 4; ++r) {
        int grow = rowBase + wave * 16 + q * 4 + r;
        float v0 = acc[0][r] + bc[0], v1 = acc[1][r] + bc[1];
        float v2 = acc[2][r] + bc[2], v3 = acc[3][r] + bc[3];
        float s = v0 + v1 + v2 + v3;
        for (int o = 1; o < 16; o <<= 1) s += __shfl_xor(s, o);
        float mu = s * (1.0f / 64.0f);
        float d0 = v0 - mu, d1 = v1 - mu, d2 = v2 - mu, d3 = v3 - mu;
        float qq = d0 * d0 + d1 * d1 + d2 * d2 + d3 * d3;
        for (int o = 1; o < 16; o <<= 1) qq += __shfl_xor(qq, o);
        float rstd = 1.0f / sqrtf(qq * (1.0f / 64.0f) + 1e-5f);
        if (grow < NODES) {
            float d2v = dinv2[grow];
            bf16* dst = h1s + (size_t)grow * 64 + c;
            dst[0]  = __float2bfloat16(lrelu(d0 * rstd * lg[0] + lb[0]) * d2v);
            dst[16] = __float2bfloat16(lrelu(d1 * rstd * lg[1] + lb[1]) * d2v);
            dst[32] = __float2bfloat16(lrelu(d2 * rstd * lg[2] + lb[2]) * d2v);
            dst[48] = __float2bfloat16(lrelu(d3 * rstd * lg[3] + lb[3]) * d2v);
        }
    }
}

// layer2: gather + MFMA + bias + leaky + run-merged max-pool
__global__ void __launch_bounds__(256, 2)
gcn2_fused(const uint2* __restrict__ h1s4, const int* __restrict__ csr,
           const int* __restrict__ rp, const float* __restrict__ dinv2,
           const float* __restrict__ W2, const float* __restrict__ b2,
           const void* __restrict__ batch, const int* __restrict__ flag,
           unsigned* __restrict__ pooled) {
    __shared__ short sm[2 * 64 * VSS];
    __shared__ int gsh[64];
    short* Vs = sm;
    short* Wt = sm + 64 * VSS;
    int t = threadIdx.x, lane = t & 63, wave = t >> 6;
    int rowBase = blockIdx.x * 64;
    if (t < 64) {
        int row = rowBase + t;
        gsh[t] = (row < NODES) ? idx_at(batch, row, flag[0]) : -1;
    }
    f32x4 acc[4];
    gcn_core(h1s4, csr, rp, dinv2, 1.0f, W2, Vs, Wt, rowBase, lane, wave, acc);
    int c = lane & 15, q = lane >> 4;
    float bc[4];
#pragma unroll
    for (int nt = 0; nt < 4; ++nt) bc[nt] = b2[nt * 16 + c];
    __syncthreads();
    float* P = (float*)sm;  // 64 x 65 fp32 pool buffer
#pragma unroll
    for (int r = 0; r < 4; ++r) {
        int mloc = wave * 16 + q * 4 + r;
#pragma unroll
        for (int nt = 0; nt < 4; ++nt)
            P[(size_t)mloc * 65 + nt * 16 + c] = lrelu(acc[nt][r] + bc[nt]);
    }
    __syncthreads();
    if (wave == 0) {
        float m = P[lane];
        int gc = gsh[0];
        for (int r = 1; r < 64; ++r) {
            int gr = gsh[r];
            float ar = P[(size_t)r * 65 + lane];
            if (gr == gc) {
                m = fmaxf(m, ar);
            } else {
                if ((unsigned)gc < NGRAPH) atomicMax(&pooled[gc * 64 + lane], mapf(m));
                gc = gr;
                m = ar;
            }
        }
        if ((unsigned)gc < NGRAPH) atomicMax(&pooled[gc * 64 + lane], mapf(m));
    }
}

// head: z = pooled@W3+b3; LN; leaky; z@W4+b4; softmax. One block per graph.
__global__ void head_kernel(const unsigned* __restrict__ pooled, const float* __restrict__ W3,
                            const float* __restrict__ b3, const float* __restrict__ g2,
                            const float* __restrict__ be2, const float* __restrict__ W4,
                            const float* __restrict__ b4, float* __restrict__ out) {
    __shared__ float prow[64];
    __shared__ float z[768];
    __shared__ float rs[4], rss[4];
    __shared__ float mu_s, rstd_s;
    __shared__ float red[10];
    int t = threadIdx.x, gI = blockIdx.x;
    if (t < 64) prow[t] = unmapf(pooled[gI * 64 + t]);
    __syncthreads();
    for (int c = t; c < 768; c += 256) {
        float acc = b3[c];
#pragma unroll 16
        for (int k = 0; k < 64; ++k) acc += prow[k] * W3[k * 768 + c];
        z[c] = acc;
    }
    __syncthreads();
    float s = 0.0f, ss = 0.0f;
    for (int c = t; c < 768; c += 256) {
        float v = z[c];
        s += v;
        ss += v * v;
    }
    for (int o = 32; o; o >>= 1) {
        s += __shfl_xor(s, o);
        ss += __shfl_xor(ss, o);
    }
    if ((t & 63) == 0) { rs[t >> 6] = s; rss[t >> 6] = ss; }
    __syncthreads();
    if (t == 0) {
        float S = rs[0] + rs[1] + rs[2] + rs[3];
        float SS = rss[0] + rss[1] + rss[2] + rss[3];
        float mu = S * (1.0f / 768.0f);
        float var = SS * (1.0f / 768.0f) - mu * mu;
        mu_s = mu;
        rstd_s = 1.0f / sqrtf(fmaxf(var, 0.0f) + 1e-5f);
    }
    __syncthreads();
    for (int c = t; c < 768; c += 256) {
        float y = (z[c] - mu_s) * rstd_s * g2[c] + be2[c];
        z[c] = lrelu(y);
    }
    if (t < 10) red[t] = 0.0f;
    __syncthreads();
    float p[10];
#pragma unroll
    for (int c = 0; c < 10; ++c) p[c] = 0.0f;
    for (int k = t; k < 768; k += 256) {
        float zv = z[k];
#pragma unroll
        for (int c = 0; c < 10; ++c) p[c] += zv * W4[k * 10 + c];
    }
#pragma unroll
    for (int c = 0; c < 10; ++c) atomicAdd(&red[c], p[c]);
    __syncthreads();
    if (t == 0) {
        float l[10], m = -1e30f;
#pragma unroll
        for (int c = 0; c < 10; ++c) {
            l[c] = red[c] + b4[c];
            m = fmaxf(m, l[c]);
        }
        float sum = 0.0f;
#pragma unroll
        for (int c = 0; c < 10; ++c) {
            l[c] = expf(l[c] - m);
            sum += l[c];
        }
        float inv = 1.0f / sum;
#pragma unroll
        for (int c = 0; c < 10; ++c) out[gI * 10 + c] = l[c] * inv;
    }
}

extern "C" void kernel_launch(void* const* d_in, const int* in_sizes, int n_in,
                              void* d_out, int out_size, void* d_ws, size_t ws_size,
                              hipStream_t stream) {
    const size_t REQUIRED = (size_t)NODES * 64 * 2 * 2   // xs + h1s (staging aliases h1s)
                          + (size_t)EDGES * 4            // csr_src
                          + (size_t)(NODES + 1) * 4      // row_ptr
                          + (size_t)NODES * 4 * 2        // dinv1, dinv2
                          + (size_t)(NBINS * 3 + 1) * 4  // binTotal, binStart, binCursor
                          + (size_t)NGRAPH * 64 * 4      // pooled
                          + 16;                          // flag
    if (ws_size < REQUIRED) {
        sentinel_kernel<<<20, 256, 0, stream>>>((float*)d_out, 64.0f);
        return;
    }

    const float* x = (const float*)d_in[0];
    const void* ei = d_in[1];
    const void* batch = d_in[2];
    const float* W1 = (const float*)d_in[3];
    const float* b1 = (const float*)d_in[4];
    const float* lng = (const float*)d_in[5];
    const float* lnb = (const float*)d_in[6];
    const float* W2 = (const float*)d_in[7];
    const float* b2 = (const float*)d_in[8];
    const float* W3 = (const float*)d_in[9];
    const float* b3 = (const float*)d_in[10];
    const float* g2 = (const float*)d_in[11];
    const float* be2 = (const float*)d_in[12];
    const float* W4 = (const float*)d_in[13];
    const float* b4 = (const float*)d_in[14];

    bf16* xs = (bf16*)d_ws;                               // N*64 bf16
    bf16* h1s = xs + (size_t)NODES * 64;                  // N*64 bf16
    unsigned* staging = (unsigned*)h1s;                   // E*4 (aliases h1s; dead by gcn1)
    int* csr_src = (int*)(h1s + (size_t)NODES * 64);      // E
    int* row_ptr = csr_src + EDGES;                       // N+1
    float* dinv1 = (float*)(row_ptr + NODES + 1);         // N
    float* dinv2 = dinv1 + NODES;                         // N
    int* binTotal = (int*)(dinv2 + NODES);                // 98
    int* binStart = binTotal + NBINS;                     // 99
    int* binCursor = binStart + NBINS + 1;                // 98
    unsigned* pooled = (unsigned*)(binCursor + NBINS);    // G*64
    int* flag = (int*)(pooled + NGRAPH * 64);             // 1

    detect_init<<<(NGRAPH * 64 + 255) / 256, 256, 0, stream>>>((const int*)ei, flag, pooled,
                                                               binTotal, binCursor);

    // CSR build: two-pass radix partition by dst>>10, then per-bin finalize
    int nchunks = (EDGES + CHUNK - 1) / CHUNK;
    binCount<<<nchunks, 256, 0, stream>>>(ei, flag, binTotal);
    scan98<<<1, 128, 0, stream>>>(binTotal, binStart, row_ptr);
    binPlace<<<nchunks, 256, 0, stream>>>(ei, flag, binStart, binCursor, staging);
    csr_finalize<<<NBINS, 256, 0, stream>>>(staging, binStart, row_ptr, dinv1, dinv2,
                                            csr_src);
    prescale_x<<<(NODES * 64 + 255) / 256, 256, 0, stream>>>(x, dinv1, xs);

    // fused layers: 64 rows/block (4 waves x 16 rows), MFMA GEMM
    gcn1_fused<<<(NODES + 63) / 64, 256, 0, stream>>>((const uint2*)xs, csr_src, row_ptr,
                                                      dinv1, dinv2, W1, b1, lng, lnb, h1s);
    gcn2_fused<<<(NODES + 63) / 64, 256, 0, stream>>>((const uint2*)h1s, csr_src, row_ptr,
                                                      dinv2, W2, b2, batch, flag, pooled);

    // head
    head_kernel<<<NGRAPH, 256, 0, stream>>>(pooled, W3, b3, g2, be2, W4, b4, (float*)d_out);
}